// Round 10
// baseline (358.345 us; speedup 1.0000x reference)
//
#include <hip/hip_runtime.h>

// HaloAttn on MI355X (gfx950). f32 in/out, bf16 MFMA internals.
// R10: R9 (BK=64, 4 K-chunks) with the B-staging bug FIXED.
//   R9 failed NaN: B loads were 16 shorts/thread (BK=32 count) against a
//   32-short need, and writes at halfA*16 left holes at [8,16)/[24,32) of each
//   half-row -> half of sB uninitialized. Now 4 uint4/thread: each thread covers
//   row tid>>1, k-shorts [half*16,+16) of BOTH 32-k sub-slabs.
//   Rationale unchanged (R8: all pipes idle, per-chunk phase overhead dominates;
//   halve phases, double MFMA per phase). XCD-gather swizzle kept. halo unchanged.

using bf16x8 = __attribute__((ext_vector_type(8))) short;
using f32x4  = __attribute__((ext_vector_type(4))) float;

__device__ __forceinline__ float bf2f(unsigned short u) {
  return __uint_as_float(((unsigned int)u) << 16);
}
__device__ __forceinline__ unsigned short f2bf(float f) {
  unsigned int x = __float_as_uint(f);
  x += 0x7fffu + ((x >> 16) & 1u);
  return (unsigned short)(x >> 16);
}
__device__ __forceinline__ unsigned int pack2(float a, float b) {
  return (unsigned int)f2bf(a) | ((unsigned int)f2bf(b) << 16);
}
__device__ __forceinline__ int div14(int p) { return (p * 4682) >> 16; }

// ---------------- pos_proj ----------------
__global__ __launch_bounds__(256) void pos_proj_kernel(
    const float* __restrict__ Wq, const float* __restrict__ Wk,
    float* __restrict__ PK, float* __restrict__ PQ) {
  __shared__ float pr[256];
  const int row = blockIdx.x, o = threadIdx.x;
  const float* Wm;
  float* dst;
  int ii, jj;
  if (row < 208) {
    if (row >= 196) { PK[row * 256 + o] = 0.f; return; }
    ii = row / 14; jj = row % 14;
    Wm = Wk; dst = PK + row * 256;
  } else {
    int qp = row - 208;
    ii = (qp >> 3) + 3; jj = (qp & 7) + 3;
    Wm = Wq; dst = PQ + qp * 256;
  }
  const int cl = o & 127, mfreq = cl >> 1;
  float t = powf(10000.f, (float)mfreq * (1.f / 64.f));
  float base = (o < 128) ? (float)(ii + 1) : (float)(jj + 1);
  float arg = base * (6.283185307179586f / 14.000001f) / t;
  pr[o] = (cl & 1) ? cosf(arg) : sinf(arg);
  __syncthreads();
  float acc = 0.f;
  for (int c = 0; c < 256; ++c) acc = fmaf(pr[c], Wm[c * 256 + o], acc);
  dst[o] = acc;
}

// ---------------- wtrans2: Wt'[mat][kc32][n][32] = bf16(W[kc32*32+kk][n]) ----------------
__global__ __launch_bounds__(256) void wtrans2_kernel(
    const float* __restrict__ Wq, const float* __restrict__ Wk,
    const float* __restrict__ Wv, const float* __restrict__ Wp,
    unsigned short* __restrict__ Wt) {
  __shared__ unsigned short sW[256 * 40];  // [n][kk], pad 40
  const int mat = blockIdx.x >> 3, kc = blockIdx.x & 7;
  const float* src = (mat == 0) ? Wq : (mat == 1) ? Wk : (mat == 2) ? Wv : Wp;
  const int tid = threadIdx.x;
  for (int t = tid; t < 2048; t += 256) {
    int k = t >> 6, sg = t & 63;
    float4 v = *(const float4*)&src[(kc * 32 + k) * 256 + sg * 4];
    sW[(sg * 4 + 0) * 40 + k] = f2bf(v.x);
    sW[(sg * 4 + 1) * 40 + k] = f2bf(v.y);
    sW[(sg * 4 + 2) * 40 + k] = f2bf(v.z);
    sW[(sg * 4 + 3) * 40 + k] = f2bf(v.w);
  }
  __syncthreads();
  unsigned short* dst = Wt + mat * 65536 + kc * 8192;
  for (int t = tid; t < 1024; t += 256) {
    int n = t >> 2, sg = t & 3;
    *(uint4*)&dst[n * 32 + sg * 8] = *(const uint4*)&sW[n * 40 + sg * 8];
  }
}

// ---------------- qkv_gemm: 1D grid 3072; M=128, N=128, K = 4 chunks of 64 ----------------
struct QkvLds {
  union {
    struct {
      unsigned short sA[128 * 72];  // A-tile bf16 [row][k64], stride 72
      unsigned short sB[128 * 72];  // B-tile bf16 [n][k64], stride 72
    } s;                            // 36,864 B
    unsigned short sT[64 * 136];    // V-transpose chunk [ch64][pix128], stride 136
  } u;
  float sPQ[8 * 128];               // PQ slice cols n0..n0+127 (mat 0 only)
};

__global__ __launch_bounds__(256, 3) void qkv_gemm_kernel(
    const float* __restrict__ xg, const unsigned short* __restrict__ Wt,
    const float* __restrict__ PQ,
    unsigned short* __restrict__ XQ, unsigned short* __restrict__ XK,
    unsigned short* __restrict__ XVt) {
  __shared__ QkvLds sm;
  const int bid = blockIdx.x;
  const int xcd = bid & 7, rowid = bid >> 3;   // rowid 0..383
  const int s6 = rowid % 6, gg = rowid / 6;    // s6: mat*2+n0half, gg 0..63
  const int g = gg * 8 + xcd;                  // m-tile 0..511
  const int mat = s6 >> 1;
  const int m0 = g << 7;
  const int n0 = (s6 & 1) << 7;
  const int tid = threadIdx.x;
  const int wave = tid >> 6, lane = tid & 63, q = lane >> 4, r = lane & 15;

  if (mat == 0) {  // stage PQ rows (y&7)*8..+8, cols n0..n0+127
    const int y7 = (m0 >> 7) & 7;
    const int rr = tid >> 5, cc = tid & 31;
    *(float4*)&sm.sPQ[rr * 128 + cc * 4] =
        *(const float4*)&PQ[(y7 * 8 + rr) * 256 + n0 + cc * 4];
  }

  const int rowA = tid >> 1, halfA = tid & 1;  // 128 rows, 2 threads/row
  const float* aptr = xg + ((m0 + rowA) << 8) + halfA * 32;           // + kc*64
  const unsigned short* bptr = Wt + mat * 65536 + n0 * 32 + tid * 16; // + sub*8192

  f32x4 acc[2][8];
#pragma unroll
  for (int mt = 0; mt < 2; ++mt)
#pragma unroll
    for (int nt = 0; nt < 8; ++nt) acc[mt][nt] = (f32x4){0.f, 0.f, 0.f, 0.f};

  float4 a0, a1, a2, a3, a4, a5, a6, a7;
  uint4 b0, b1, b2, b3;

#define QKV_LOAD(KC)                                        \
  {                                                         \
    const float* ap_ = aptr + (KC) * 64;                    \
    a0 = *(const float4*)(ap_ + 0);                         \
    a1 = *(const float4*)(ap_ + 4);                         \
    a2 = *(const float4*)(ap_ + 8);                         \
    a3 = *(const float4*)(ap_ + 12);                        \
    a4 = *(const float4*)(ap_ + 16);                        \
    a5 = *(const float4*)(ap_ + 20);                        \
    a6 = *(const float4*)(ap_ + 24);                        \
    a7 = *(const float4*)(ap_ + 28);                        \
    const unsigned short* bp0_ = bptr + (2 * (KC)) * 8192;  \
    const unsigned short* bp1_ = bp0_ + 8192;               \
    b0 = *(const uint4*)(bp0_);                             \
    b1 = *(const uint4*)(bp0_ + 8);                         \
    b2 = *(const uint4*)(bp1_);                             \
    b3 = *(const uint4*)(bp1_ + 8);                         \
  }

#define QKV_PACKWRITE()                                                   \
  {                                                                       \
    const int abase_ = rowA * 72 + halfA * 32;                            \
    uint4 w_;                                                             \
    w_.x = pack2(a0.x, a0.y); w_.y = pack2(a0.z, a0.w);                   \
    w_.z = pack2(a1.x, a1.y); w_.w = pack2(a1.z, a1.w);                   \
    *(uint4*)&sm.u.s.sA[abase_ + 0] = w_;                                 \
    w_.x = pack2(a2.x, a2.y); w_.y = pack2(a2.z, a2.w);                   \
    w_.z = pack2(a3.x, a3.y); w_.w = pack2(a3.z, a3.w);                   \
    *(uint4*)&sm.u.s.sA[abase_ + 8] = w_;                                 \
    w_.x = pack2(a4.x, a4.y); w_.y = pack2(a4.z, a4.w);                   \
    w_.z = pack2(a5.x, a5.y); w_.w = pack2(a5.z, a5.w);                   \
    *(uint4*)&sm.u.s.sA[abase_ + 16] = w_;                                \
    w_.x = pack2(a6.x, a6.y); w_.y = pack2(a6.z, a6.w);                   \
    w_.z = pack2(a7.x, a7.y); w_.w = pack2(a7.z, a7.w);                   \
    *(uint4*)&sm.u.s.sA[abase_ + 24] = w_;                                \
    const int bbase_ = rowA * 72 + halfA * 16;                            \
    *(uint4*)&sm.u.s.sB[bbase_ + 0] = b0;                                 \
    *(uint4*)&sm.u.s.sB[bbase_ + 8] = b1;                                 \
    *(uint4*)&sm.u.s.sB[bbase_ + 32] = b2;                                \
    *(uint4*)&sm.u.s.sB[bbase_ + 40] = b3;                                \
  }

  QKV_LOAD(0)

  for (int kc = 0; kc < 4; ++kc) {
    if (kc) __syncthreads();  // frag reads of kc-1 complete
    QKV_PACKWRITE()
    __syncthreads();
    if (kc < 3) QKV_LOAD(kc + 1)  // in flight during 32 MFMAs + barrier
    bf16x8 a00 = *(const bf16x8*)&sm.u.s.sA[(wave * 32 + r) * 72 + q * 8];
    bf16x8 a01 = *(const bf16x8*)&sm.u.s.sA[(wave * 32 + r) * 72 + 32 + q * 8];
    bf16x8 a10 = *(const bf16x8*)&sm.u.s.sA[(wave * 32 + 16 + r) * 72 + q * 8];
    bf16x8 a11 = *(const bf16x8*)&sm.u.s.sA[(wave * 32 + 16 + r) * 72 + 32 + q * 8];
#pragma unroll
    for (int nt = 0; nt < 8; ++nt) {
      bf16x8 bw0 = *(const bf16x8*)&sm.u.s.sB[(nt * 16 + r) * 72 + q * 8];
      bf16x8 bw1 = *(const bf16x8*)&sm.u.s.sB[(nt * 16 + r) * 72 + 32 + q * 8];
      acc[0][nt] = __builtin_amdgcn_mfma_f32_16x16x32_bf16(a00, bw0, acc[0][nt], 0, 0, 0);
      acc[0][nt] = __builtin_amdgcn_mfma_f32_16x16x32_bf16(a01, bw1, acc[0][nt], 0, 0, 0);
      acc[1][nt] = __builtin_amdgcn_mfma_f32_16x16x32_bf16(a10, bw0, acc[1][nt], 0, 0, 0);
      acc[1][nt] = __builtin_amdgcn_mfma_f32_16x16x32_bf16(a11, bw1, acc[1][nt], 0, 0, 0);
    }
  }
#undef QKV_LOAD
#undef QKV_PACKWRITE

  if (mat == 2) {
    // V transposed store via LDS: 2 chunks of 64 channels (n0 half), coalesced rows
    __syncthreads();  // all LDS frag reads done before sT overwrite
#pragma unroll
    for (int c4 = 0; c4 < 2; ++c4) {
      if (c4) __syncthreads();
#pragma unroll
      for (int mt = 0; mt < 2; ++mt)
#pragma unroll
        for (int n4 = 0; n4 < 4; ++n4) {
          int ch = n4 * 16 + r;
          int prb = wave * 32 + mt * 16 + q * 4;
          uint2 w;
          w.x = pack2(acc[mt][c4 * 4 + n4][0], acc[mt][c4 * 4 + n4][1]);
          w.y = pack2(acc[mt][c4 * 4 + n4][2], acc[mt][c4 * 4 + n4][3]);
          *(uint2*)&sm.u.sT[ch * 136 + prb] = w;
        }
      __syncthreads();
      for (int t = tid; t < 1024; t += 256) {
        int ch = t >> 4, sg = t & 15;
        *(uint4*)&XVt[((n0 + c4 * 64 + ch) << 16) + m0 + sg * 8] =
            *(const uint4*)&sm.u.sT[ch * 136 + sg * 8];
      }
    }
  } else {
    unsigned short* dst = (mat == 0) ? XQ : XK;
#pragma unroll
    for (int mt = 0; mt < 2; ++mt)
#pragma unroll
      for (int nt = 0; nt < 8; ++nt)
#pragma unroll
        for (int g2 = 0; g2 < 4; ++g2) {
          int lrow = wave * 32 + mt * 16 + q * 4 + g2;
          float v = acc[mt][nt][g2];
          if (mat == 0) v += sm.sPQ[(lrow & 7) * 128 + nt * 16 + r];
          dst[((m0 + lrow) << 8) + n0 + nt * 16 + r] = f2bf(v);
        }
  }
}

// ---------------- halo: one WG per (window, head); grid 8192 (unchanged) ----------------
struct alignas(16) SMH {
  unsigned short sK[196 * 40];
  unsigned short sVt[32 * 232];
  unsigned short sU[64 * 40];
};

__global__ __launch_bounds__(256, 4) void halo_kernel(
    const unsigned short* XQ,           // aliases XO
    const unsigned short* __restrict__ XK,
    const unsigned short* __restrict__ XVt,
    const float* __restrict__ PK,
    unsigned short* XO) {
  __shared__ SMH sm;
  const int wid = blockIdx.x;
  const int h = wid & 7, win = wid >> 3;
  const int b = win >> 8, widx = win & 255;
  const int wy = widx >> 4, wx = widx & 15;
  const int hc = h * 32;
  const int tid = threadIdx.x;
  const int wave = tid >> 6, lane = tid & 63, q = lane >> 4, r = lane & 15;
  const bool interior = (unsigned)(wy - 1) < 14u && (unsigned)(wx - 1) < 14u;
  const int ybase = wy * 8 - 3, xbase = wx * 8 - 3;
  constexpr float SCALE = 0.17677669529663687f;

  for (int idx = tid; idx < 1152; idx += 256) {
    int rr = idx / 36, c2 = idx - rr * 36;
    sm.sVt[rr * 232 + 196 + c2] = 0;
  }

  if (interior) {
    for (int t = tid; t < 784; t += 256) {
      int p = t >> 2, seg = t & 3;
      int i = div14(p), j = p - i * 14;
      int pix = (b * 128 + ybase + i) * 128 + xbase + j;
      bf16x8 kv = *(const bf16x8*)&XK[(pix << 8) + hc + seg * 8];
      const float4* pk4 = (const float4*)(PK + (p << 8) + hc + seg * 8);
      float4 f0 = pk4[0], f1 = pk4[1];
      uint4 w;
      w.x = pack2(bf2f((unsigned short)kv[0]) + f0.x, bf2f((unsigned short)kv[1]) + f0.y);
      w.y = pack2(bf2f((unsigned short)kv[2]) + f0.z, bf2f((unsigned short)kv[3]) + f0.w);
      w.z = pack2(bf2f((unsigned short)kv[4]) + f1.x, bf2f((unsigned short)kv[5]) + f1.y);
      w.w = pack2(bf2f((unsigned short)kv[6]) + f1.z, bf2f((unsigned short)kv[7]) + f1.w);
      *(uint4*)&sm.sK[p * 40 + seg * 8] = w;
    }
    for (int t = tid; t < 448; t += 256) {
      int c = div14(t), i = t - c * 14;
      int pix0 = (b * 128 + ybase + i) * 128 + xbase;
      const unsigned int* src = (const unsigned int*)(XVt + ((hc + c) << 16) + pix0 - 1);
      unsigned int d[8];
#pragma unroll
      for (int k = 0; k < 8; ++k) d[k] = src[k];
      int base = c * 232 + i * 14;
#pragma unroll
      for (int k = 0; k < 7; ++k)
        *(unsigned int*)&sm.sVt[base + k * 2] = (d[k] >> 16) | (d[k + 1] << 16);
    }
  } else {
    for (int t = tid; t < 784; t += 256) {
      int p = t >> 2, seg = t & 3;
      int i = div14(p), j = p - i * 14;
      int y = ybase + i, x = xbase + j;
      uint4 w = {0u, 0u, 0u, 0u};
      if ((unsigned)y < 128u && (unsigned)x < 128u) {
        int pix = (b * 128 + y) * 128 + x;
        bf16x8 kv = *(const bf16x8*)&XK[(pix << 8) + hc + seg * 8];
        const float4* pk4 = (const float4*)(PK + (p << 8) + hc + seg * 8);
        float4 f0 = pk4[0], f1 = pk4[1];
        w.x = pack2(bf2f((unsigned short)kv[0]) + f0.x, bf2f((unsigned short)kv[1]) + f0.y);
        w.y = pack2(bf2f((unsigned short)kv[2]) + f0.z, bf2f((unsigned short)kv[3]) + f0.w);
        w.z = pack2(bf2f((unsigned short)kv[4]) + f1.x, bf2f((unsigned short)kv[5]) + f1.y);
        w.w = pack2(bf2f((unsigned short)kv[6]) + f1.z, bf2f((unsigned short)kv[7]) + f1.w);
      }
      *(uint4*)&sm.sK[p * 40 + seg * 8] = w;
    }
    for (int t = tid; t < 448; t += 256) {
      int c = div14(t), i = t - c * 14;
      int y = ybase + i;
      unsigned int o[7] = {0u, 0u, 0u, 0u, 0u, 0u, 0u};
      if ((unsigned)y < 128u) {
        const unsigned short* row = XVt + ((hc + c) << 16) + (b * 128 + y) * 128;
#pragma unroll
        for (int k = 0; k < 7; ++k) {
          int x0 = xbase + 2 * k, x1 = x0 + 1;
          unsigned int lo = ((unsigned)x0 < 128u) ? row[x0] : 0u;
          unsigned int hi = ((unsigned)x1 < 128u) ? row[x1] : 0u;
          o[k] = lo | (hi << 16);
        }
      }
      int base = c * 232 + i * 14;
#pragma unroll
      for (int k = 0; k < 7; ++k) *(unsigned int*)&sm.sVt[base + k * 2] = o[k];
    }
  }
  {
    int m = tid >> 2, seg = tid & 3;
    int pix = (b * 128 + wy * 8 + (m >> 3)) * 128 + wx * 8 + (m & 7);
    *(uint4*)&sm.sU[m * 40 + seg * 8] = *(const uint4*)&XQ[(pix << 8) + hc + seg * 8];
  }
  __syncthreads();

  bf16x8 aq = *(const bf16x8*)&sm.sU[(wave * 16 + r) * 40 + q * 8];
  f32x4 s[14];
#pragma unroll
  for (int nt = 0; nt < 14; ++nt) {
    bf16x8 bk = *(const bf16x8*)&sm.sK[(nt * 16 + r) * 40 + q * 8];
    f32x4 z = {0.f, 0.f, 0.f, 0.f};
    s[nt] = __builtin_amdgcn_mfma_f32_16x16x32_bf16(aq, bk, z, 0, 0, 0);
  }
  if (interior) {
#pragma unroll
    for (int nt = 0; nt < 12; ++nt)
#pragma unroll
      for (int g = 0; g < 4; ++g) s[nt][g] *= SCALE;
#pragma unroll
    for (int g = 0; g < 4; ++g) {
      s[12][g] = (r < 4) ? s[12][g] * SCALE : -1e30f;
      s[13][g] = -1e30f;
    }
  } else {
#pragma unroll
    for (int nt = 0; nt < 14; ++nt) {
      int n = nt * 16 + r;
      int i = div14(n), j = n - i * 14;
      int y = ybase + i, x = xbase + j;
      bool valid = (n < 196) && ((unsigned)y < 128u) && ((unsigned)x < 128u);
#pragma unroll
      for (int g = 0; g < 4; ++g) s[nt][g] = valid ? s[nt][g] * SCALE : -1e30f;
    }
  }
  float mx[4] = {-1e30f, -1e30f, -1e30f, -1e30f};
#pragma unroll
  for (int nt = 0; nt < 14; ++nt)
#pragma unroll
    for (int g = 0; g < 4; ++g) mx[g] = fmaxf(mx[g], s[nt][g]);
#pragma unroll
  for (int d = 1; d < 16; d <<= 1)
#pragma unroll
    for (int g = 0; g < 4; ++g) mx[g] = fmaxf(mx[g], __shfl_xor(mx[g], d));
  float sum[4] = {0.f, 0.f, 0.f, 0.f};
#pragma unroll
  for (int nt = 0; nt < 14; ++nt)
#pragma unroll
    for (int g = 0; g < 4; ++g) {
      float e = __expf(s[nt][g] - mx[g]);
      s[nt][g] = e; sum[g] += e;
    }
#pragma unroll
  for (int d = 1; d < 16; d <<= 1)
#pragma unroll
    for (int g = 0; g < 4; ++g) sum[g] += __shfl_xor(sum[g], d);
  float inv[4];
#pragma unroll
  for (int g = 0; g < 4; ++g) inv[g] = 1.f / sum[g];
#pragma unroll
  for (int nt = 0; nt < 14; ++nt)
#pragma unroll
    for (int g = 0; g < 4; ++g) s[nt][g] *= inv[g];

  f32x4 ov[2];
  ov[0] = (f32x4){0.f, 0.f, 0.f, 0.f}; ov[1] = ov[0];
#pragma unroll
  for (int ck = 0; ck < 7; ++ck) {
#pragma unroll
    for (int tq = 0; tq < 2; ++tq)
#pragma unroll
      for (int g = 0; g < 4; ++g)
        sm.sU[(wave * 16 + q * 4 + g) * 40 + tq * 16 + r] = f2bf(s[ck * 2 + tq][g]);
    bf16x8 ap = *(const bf16x8*)&sm.sU[(wave * 16 + r) * 40 + q * 8];
#pragma unroll
    for (int t2 = 0; t2 < 2; ++t2) {
      bf16x8 bv = *(const bf16x8*)&sm.sVt[(t2 * 16 + r) * 232 + ck * 32 + q * 8];
      ov[t2] = __builtin_amdgcn_mfma_f32_16x16x32_bf16(ap, bv, ov[t2], 0, 0, 0);
    }
  }
#pragma unroll
  for (int t2 = 0; t2 < 2; ++t2)
#pragma unroll
    for (int g = 0; g < 4; ++g)
      sm.sU[(wave * 16 + q * 4 + g) * 40 + t2 * 16 + r] = f2bf(ov[t2][g]);
  {
    int m = tid >> 2, seg = tid & 3;
    int pix = (b * 128 + wy * 8 + (m >> 3)) * 128 + wx * 8 + (m & 7);
    bf16x8 o8 = *(const bf16x8*)&sm.sU[m * 40 + seg * 8];
    *(uint4*)&XO[(pix << 8) + hc + seg * 8] = *(uint4*)&o8;
  }
}

// ---------------- out_proj: 1D grid 1024; M=128, N=128, K = 4 chunks of 64 ----------------
__global__ __launch_bounds__(256, 3) void out_proj_kernel(
    const unsigned short* __restrict__ XO, const unsigned short* __restrict__ Wt,
    const float* __restrict__ bp, float* __restrict__ out) {
  __shared__ unsigned short sA[128 * 72];
  __shared__ unsigned short sB[128 * 72];
  const int bid = blockIdx.x;
  const int xcd = bid & 7, rowid = bid >> 3;  // rowid 0..127
  const int s2 = rowid & 1, gg = rowid >> 1;  // gg 0..63
  const int g = gg * 8 + xcd;                 // m-tile 0..511
  const int m0 = g << 7, n0 = s2 << 7;
  const int tid = threadIdx.x;
  const int wave = tid >> 6, lane = tid & 63, q = lane >> 4, r = lane & 15;

  const int rowA = tid >> 1, halfA = tid & 1;
  const unsigned short* aptr = XO + ((m0 + rowA) << 8) + halfA * 32;   // + kc*64
  const unsigned short* bptr = Wt + 3 * 65536 + n0 * 32 + tid * 16;    // + sub*8192

  f32x4 acc[2][8];
#pragma unroll
  for (int nt = 0; nt < 8; ++nt) {
    float bv = bp[n0 + nt * 16 + r];
    acc[0][nt] = (f32x4){bv, bv, bv, bv};
    acc[1][nt] = (f32x4){bv, bv, bv, bv};
  }

  uint4 pa0, pa1, pa2, pa3, b0, b1, b2, b3;

#define OP_LOAD(KC)                                         \
  {                                                         \
    const unsigned short* ap_ = aptr + (KC) * 64;           \
    pa0 = *(const uint4*)(ap_ + 0);                         \
    pa1 = *(const uint4*)(ap_ + 8);                         \
    pa2 = *(const uint4*)(ap_ + 16);                        \
    pa3 = *(const uint4*)(ap_ + 24);                        \
    const unsigned short* bp0_ = bptr + (2 * (KC)) * 8192;  \
    const unsigned short* bp1_ = bp0_ + 8192;               \
    b0 = *(const uint4*)(bp0_);                             \
    b1 = *(const uint4*)(bp0_ + 8);                         \
    b2 = *(const uint4*)(bp1_);                             \
    b3 = *(const uint4*)(bp1_ + 8);                         \
  }

#define OP_WRITE()                                          \
  {                                                         \
    const int abase_ = rowA * 72 + halfA * 32;              \
    *(uint4*)&sA[abase_ + 0] = pa0;                         \
    *(uint4*)&sA[abase_ + 8] = pa1;                         \
    *(uint4*)&sA[abase_ + 16] = pa2;                        \
    *(uint4*)&sA[abase_ + 24] = pa3;                        \
    const int bbase_ = rowA * 72 + halfA * 16;              \
    *(uint4*)&sB[bbase_ + 0] = b0;                          \
    *(uint4*)&sB[bbase_ + 8] = b1;                          \
    *(uint4*)&sB[bbase_ + 32] = b2;                         \
    *(uint4*)&sB[bbase_ + 40] = b3;                         \
  }

  OP_LOAD(0)

  for (int kc = 0; kc < 4; ++kc) {
    if (kc) __syncthreads();
    OP_WRITE()
    __syncthreads();
    if (kc < 3) OP_LOAD(kc + 1)
    bf16x8 a00 = *(const bf16x8*)&sA[(wave * 32 + r) * 72 + q * 8];
    bf16x8 a01 = *(const bf16x8*)&sA[(wave * 32 + r) * 72 + 32 + q * 8];
    bf16x8 a10 = *(const bf16x8*)&sA[(wave * 32 + 16 + r) * 72 + q * 8];
    bf16x8 a11 = *(const bf16x8*)&sA[(wave * 32 + 16 + r) * 72 + 32 + q * 8];
#pragma unroll
    for (int nt = 0; nt < 8; ++nt) {
      bf16x8 bw0 = *(const bf16x8*)&sB[(nt * 16 + r) * 72 + q * 8];
      bf16x8 bw1 = *(const bf16x8*)&sB[(nt * 16 + r) * 72 + 32 + q * 8];
      acc[0][nt] = __builtin_amdgcn_mfma_f32_16x16x32_bf16(a00, bw0, acc[0][nt], 0, 0, 0);
      acc[0][nt] = __builtin_amdgcn_mfma_f32_16x16x32_bf16(a01, bw1, acc[0][nt], 0, 0, 0);
      acc[1][nt] = __builtin_amdgcn_mfma_f32_16x16x32_bf16(a10, bw0, acc[1][nt], 0, 0, 0);
      acc[1][nt] = __builtin_amdgcn_mfma_f32_16x16x32_bf16(a11, bw1, acc[1][nt], 0, 0, 0);
    }
  }
#undef OP_LOAD
#undef OP_WRITE

#pragma unroll
  for (int mt = 0; mt < 2; ++mt)
#pragma unroll
    for (int nt = 0; nt < 8; ++nt)
#pragma unroll
      for (int g2 = 0; g2 < 4; ++g2) {
        int row = m0 + wave * 32 + mt * 16 + q * 4 + g2;
        out[(row << 8) + n0 + nt * 16 + r] = acc[mt][nt][g2];
      }
}

extern "C" void kernel_launch(void* const* d_in, const int* in_sizes, int n_in,
                              void* d_out, int out_size, void* d_ws, size_t ws_size,
                              hipStream_t stream) {
  (void)in_sizes; (void)n_in; (void)out_size;
  const float* xg = (const float*)d_in[0];
  const float* Wq = (const float*)d_in[1];
  const float* Wk = (const float*)d_in[2];
  const float* Wv = (const float*)d_in[3];
  const float* Wp = (const float*)d_in[4];
  const float* bp = (const float*)d_in[5];
  float* out = (float*)d_out;

  // ws layout (bytes), NEED = 101466112:
  //   XQO 0..33554432 | XK ..67108864 | XVt ..100663296 | Wt' ..101187584
  //   PK ..101400576 | PQ ..101466112
  if (ws_size < 101466112u) return;

  char* ws = (char*)d_ws;
  unsigned short* XQO = (unsigned short*)(ws);
  unsigned short* XK  = (unsigned short*)(ws + 33554432u);
  unsigned short* XVt = (unsigned short*)(ws + 67108864u);
  unsigned short* Wt  = (unsigned short*)(ws + 100663296u);
  float* PK = (float*)(ws + 101187584u);
  float* PQ = (float*)(ws + 101400576u);

  pos_proj_kernel<<<dim3(272), dim3(256), 0, stream>>>(Wq, Wk, PK, PQ);
  wtrans2_kernel<<<dim3(32), dim3(256), 0, stream>>>(Wq, Wk, Wv, Wp, Wt);
  qkv_gemm_kernel<<<dim3(3072), dim3(256), 0, stream>>>(xg, Wt, PQ, XQO, XK, XVt);
  halo_kernel<<<dim3(8192), dim3(256), 0, stream>>>(XQO, XK, XVt, PK, XQO);
  out_proj_kernel<<<dim3(1024), dim3(256), 0, stream>>>(XQO, Wt, bp, out);
}

// Round 11
// 321.877 us; speedup vs baseline: 1.1133x; 1.1133x over previous
//
#include <hip/hip_runtime.h>

// HaloAttn on MI355X (gfx950). f32 in/out, bf16 MFMA internals.
// R11: qkv_gemm/out_proj reverted to R8 exactly (BK=32, 1-deep prefetch —
//   R9/R10's BK=64 spilled: WRITE 98->150MB, qkv 104->150us; R7's dbuf same).
//   NEW: halo head-gather XCD swizzle — all 8 heads of a window (which read
//   interleaved 64B slices of the SAME K/V pixel rows, sharing 128B lines)
//   now land on one XCD 8 ids apart, instead of round-robin across 8 L2s.
//   qkv XCD-gather swizzle kept (FETCH 198->35MB, free).

using bf16x8 = __attribute__((ext_vector_type(8))) short;
using f32x4  = __attribute__((ext_vector_type(4))) float;

__device__ __forceinline__ float bf2f(unsigned short u) {
  return __uint_as_float(((unsigned int)u) << 16);
}
__device__ __forceinline__ unsigned short f2bf(float f) {
  unsigned int x = __float_as_uint(f);
  x += 0x7fffu + ((x >> 16) & 1u);
  return (unsigned short)(x >> 16);
}
__device__ __forceinline__ unsigned int pack2(float a, float b) {
  return (unsigned int)f2bf(a) | ((unsigned int)f2bf(b) << 16);
}
__device__ __forceinline__ int div14(int p) { return (p * 4682) >> 16; }

// ---------------- pos_proj ----------------
__global__ __launch_bounds__(256) void pos_proj_kernel(
    const float* __restrict__ Wq, const float* __restrict__ Wk,
    float* __restrict__ PK, float* __restrict__ PQ) {
  __shared__ float pr[256];
  const int row = blockIdx.x, o = threadIdx.x;
  const float* Wm;
  float* dst;
  int ii, jj;
  if (row < 208) {
    if (row >= 196) { PK[row * 256 + o] = 0.f; return; }
    ii = row / 14; jj = row % 14;
    Wm = Wk; dst = PK + row * 256;
  } else {
    int qp = row - 208;
    ii = (qp >> 3) + 3; jj = (qp & 7) + 3;
    Wm = Wq; dst = PQ + qp * 256;
  }
  const int cl = o & 127, mfreq = cl >> 1;
  float t = powf(10000.f, (float)mfreq * (1.f / 64.f));
  float base = (o < 128) ? (float)(ii + 1) : (float)(jj + 1);
  float arg = base * (6.283185307179586f / 14.000001f) / t;
  pr[o] = (cl & 1) ? cosf(arg) : sinf(arg);
  __syncthreads();
  float acc = 0.f;
  for (int c = 0; c < 256; ++c) acc = fmaf(pr[c], Wm[c * 256 + o], acc);
  dst[o] = acc;
}

// ---------------- wtrans2: Wt'[mat][kc][n][32] = bf16(W[kc*32+kk][n]) ----------------
__global__ __launch_bounds__(256) void wtrans2_kernel(
    const float* __restrict__ Wq, const float* __restrict__ Wk,
    const float* __restrict__ Wv, const float* __restrict__ Wp,
    unsigned short* __restrict__ Wt) {
  __shared__ unsigned short sW[256 * 40];  // [n][kk], pad 40
  const int mat = blockIdx.x >> 3, kc = blockIdx.x & 7;
  const float* src = (mat == 0) ? Wq : (mat == 1) ? Wk : (mat == 2) ? Wv : Wp;
  const int tid = threadIdx.x;
  for (int t = tid; t < 2048; t += 256) {
    int k = t >> 6, sg = t & 63;
    float4 v = *(const float4*)&src[(kc * 32 + k) * 256 + sg * 4];
    sW[(sg * 4 + 0) * 40 + k] = f2bf(v.x);
    sW[(sg * 4 + 1) * 40 + k] = f2bf(v.y);
    sW[(sg * 4 + 2) * 40 + k] = f2bf(v.z);
    sW[(sg * 4 + 3) * 40 + k] = f2bf(v.w);
  }
  __syncthreads();
  unsigned short* dst = Wt + mat * 65536 + kc * 8192;
  for (int t = tid; t < 1024; t += 256) {
    int n = t >> 2, sg = t & 3;
    *(uint4*)&dst[n * 32 + sg * 8] = *(const uint4*)&sW[n * 40 + sg * 8];
  }
}

// ---------------- qkv_gemm: 1D grid 3072; M=128, N=128, K in 8 chunks of 32 ----------------
// XCD-gather decode: the 6 blocks (s=mat*2+n0half) of m-tile g sit at ids
// {(6*(g/8)+s)*8 + g%8} -> same XCD, <=48 ids apart.
struct QkvLds {
  union {
    struct {
      unsigned short sA[128 * 40];  // A-tile bf16 [row][k32], stride 40
      unsigned short sB[128 * 40];  // B-tile bf16 [n][k32], stride 40
    } s;
    unsigned short sT[64 * 136];    // V-transpose chunk [ch64][pix128], stride 136
  } u;
  float sPQ[8 * 128];               // PQ slice cols n0..n0+127 (mat 0 only)
};

__global__ __launch_bounds__(256, 3) void qkv_gemm_kernel(
    const float* __restrict__ xg, const unsigned short* __restrict__ Wt,
    const float* __restrict__ PQ,
    unsigned short* __restrict__ XQ, unsigned short* __restrict__ XK,
    unsigned short* __restrict__ XVt) {
  __shared__ QkvLds sm;
  const int bid = blockIdx.x;
  const int xcd = bid & 7, rowid = bid >> 3;   // rowid 0..383
  const int s6 = rowid % 6, gg = rowid / 6;    // s6: mat*2+n0half, gg 0..63
  const int g = gg * 8 + xcd;                  // m-tile 0..511
  const int mat = s6 >> 1;
  const int m0 = g << 7;
  const int n0 = (s6 & 1) << 7;
  const int tid = threadIdx.x;
  const int wave = tid >> 6, lane = tid & 63, q = lane >> 4, r = lane & 15;

  if (mat == 0) {  // stage PQ rows (y&7)*8..+8, cols n0..n0+127
    const int y7 = (m0 >> 7) & 7;
    const int rr = tid >> 5, cc = tid & 31;
    *(float4*)&sm.sPQ[rr * 128 + cc * 4] =
        *(const float4*)&PQ[(y7 * 8 + rr) * 256 + n0 + cc * 4];
  }

  const int rowA = tid >> 2, segA = tid & 3;
  const float* aptr = xg + ((m0 + rowA) << 8) + segA * 8;  // + kc*32
  const int rowB = tid >> 1, segB = (tid & 1) << 4;
  const unsigned short* bptr = Wt + mat * 65536 + n0 * 32 + tid * 16;  // + kc*8192

  f32x4 acc[2][8];
#pragma unroll
  for (int mt = 0; mt < 2; ++mt)
#pragma unroll
    for (int nt = 0; nt < 8; ++nt) acc[mt][nt] = (f32x4){0.f, 0.f, 0.f, 0.f};

  // prefetch chunk 0
  float4 a00 = *(const float4*)(aptr);
  float4 a01 = *(const float4*)(aptr + 4);
  float4 a10 = *(const float4*)(aptr + 16384);
  float4 a11 = *(const float4*)(aptr + 16384 + 4);
  uint4 b0 = *(const uint4*)(bptr);
  uint4 b1 = *(const uint4*)(bptr + 8);

  for (int kc = 0; kc < 8; ++kc) {
    if (kc) __syncthreads();  // frag reads of kc-1 complete
    {
      uint4 w;
      w.x = pack2(a00.x, a00.y); w.y = pack2(a00.z, a00.w);
      w.z = pack2(a01.x, a01.y); w.w = pack2(a01.z, a01.w);
      *(uint4*)&sm.u.s.sA[rowA * 40 + segA * 8] = w;
      w.x = pack2(a10.x, a10.y); w.y = pack2(a10.z, a10.w);
      w.z = pack2(a11.x, a11.y); w.w = pack2(a11.z, a11.w);
      *(uint4*)&sm.u.s.sA[(rowA + 64) * 40 + segA * 8] = w;
      *(uint4*)&sm.u.s.sB[rowB * 40 + segB] = b0;
      *(uint4*)&sm.u.s.sB[rowB * 40 + segB + 8] = b1;
    }
    __syncthreads();
    if (kc < 7) {  // issue next-chunk loads; in flight during MFMAs + barrier
      const float* ap = aptr + (kc + 1) * 32;
      a00 = *(const float4*)(ap);
      a01 = *(const float4*)(ap + 4);
      a10 = *(const float4*)(ap + 16384);
      a11 = *(const float4*)(ap + 16384 + 4);
      const unsigned short* bp = bptr + (kc + 1) * 8192;
      b0 = *(const uint4*)(bp);
      b1 = *(const uint4*)(bp + 8);
    }
    bf16x8 a0 = *(const bf16x8*)&sm.u.s.sA[(wave * 32 + r) * 40 + q * 8];
    bf16x8 a1 = *(const bf16x8*)&sm.u.s.sA[(wave * 32 + 16 + r) * 40 + q * 8];
#pragma unroll
    for (int nt = 0; nt < 8; ++nt) {
      bf16x8 bw = *(const bf16x8*)&sm.u.s.sB[(nt * 16 + r) * 40 + q * 8];
      acc[0][nt] = __builtin_amdgcn_mfma_f32_16x16x32_bf16(a0, bw, acc[0][nt], 0, 0, 0);
      acc[1][nt] = __builtin_amdgcn_mfma_f32_16x16x32_bf16(a1, bw, acc[1][nt], 0, 0, 0);
    }
  }

  if (mat == 2) {
    // V transposed store via LDS: 2 chunks of 64 channels (n0 half), coalesced rows
    __syncthreads();  // all LDS frag reads done before sT overwrite
#pragma unroll
    for (int c4 = 0; c4 < 2; ++c4) {
      if (c4) __syncthreads();
#pragma unroll
      for (int mt = 0; mt < 2; ++mt)
#pragma unroll
        for (int n4 = 0; n4 < 4; ++n4)
#pragma unroll
          for (int g2 = 0; g2 < 4; ++g2) {
            int ch = n4 * 16 + r;
            int pr = wave * 32 + mt * 16 + q * 4 + g2;
            sm.u.sT[ch * 136 + pr] = f2bf(acc[mt][c4 * 4 + n4][g2]);
          }
      __syncthreads();
      for (int t = tid; t < 1024; t += 256) {
        int ch = t >> 4, sg = t & 15;
        *(uint4*)&XVt[((n0 + c4 * 64 + ch) << 16) + m0 + sg * 8] =
            *(const uint4*)&sm.u.sT[ch * 136 + sg * 8];
      }
    }
  } else {
    unsigned short* dst = (mat == 0) ? XQ : XK;
#pragma unroll
    for (int mt = 0; mt < 2; ++mt)
#pragma unroll
      for (int nt = 0; nt < 8; ++nt)
#pragma unroll
        for (int g2 = 0; g2 < 4; ++g2) {
          int lrow = wave * 32 + mt * 16 + q * 4 + g2;
          float v = acc[mt][nt][g2];
          if (mat == 0) v += sm.sPQ[(lrow & 7) * 128 + nt * 16 + r];
          dst[((m0 + lrow) << 8) + n0 + nt * 16 + r] = f2bf(v);
        }
  }
}

// ---------------- halo: one WG per (window, head); grid 8192 ----------------
// R11: head-gather XCD swizzle. bid -> xcd = bid&7, h = (bid>>3)&7,
// win = (bid>>6)*8 + xcd. All 8 heads of a window share an XCD, 8 ids apart.
struct alignas(16) SMH {
  unsigned short sK[196 * 40];
  unsigned short sVt[32 * 232];
  unsigned short sU[64 * 40];
};

__global__ __launch_bounds__(256, 4) void halo_kernel(
    const unsigned short* XQ,           // aliases XO
    const unsigned short* __restrict__ XK,
    const unsigned short* __restrict__ XVt,
    const float* __restrict__ PK,
    unsigned short* XO) {
  __shared__ SMH sm;
  const int bid = blockIdx.x;
  const int xcd = bid & 7, t8 = bid >> 3;
  const int h = t8 & 7, wgrp = t8 >> 3;       // wgrp 0..127
  const int win = wgrp * 8 + xcd;             // 0..1023 (bijective)
  const int b = win >> 8, widx = win & 255;
  const int wy = widx >> 4, wx = widx & 15;
  const int hc = h * 32;
  const int tid = threadIdx.x;
  const int wave = tid >> 6, lane = tid & 63, q = lane >> 4, r = lane & 15;
  const bool interior = (unsigned)(wy - 1) < 14u && (unsigned)(wx - 1) < 14u;
  const int ybase = wy * 8 - 3, xbase = wx * 8 - 3;
  constexpr float SCALE = 0.17677669529663687f;

  for (int idx = tid; idx < 1152; idx += 256) {
    int rr = idx / 36, c2 = idx - rr * 36;
    sm.sVt[rr * 232 + 196 + c2] = 0;
  }

  if (interior) {
    for (int t = tid; t < 784; t += 256) {
      int p = t >> 2, seg = t & 3;
      int i = div14(p), j = p - i * 14;
      int pix = (b * 128 + ybase + i) * 128 + xbase + j;
      bf16x8 kv = *(const bf16x8*)&XK[(pix << 8) + hc + seg * 8];
      const float4* pk4 = (const float4*)(PK + (p << 8) + hc + seg * 8);
      float4 f0 = pk4[0], f1 = pk4[1];
      uint4 w;
      w.x = pack2(bf2f((unsigned short)kv[0]) + f0.x, bf2f((unsigned short)kv[1]) + f0.y);
      w.y = pack2(bf2f((unsigned short)kv[2]) + f0.z, bf2f((unsigned short)kv[3]) + f0.w);
      w.z = pack2(bf2f((unsigned short)kv[4]) + f1.x, bf2f((unsigned short)kv[5]) + f1.y);
      w.w = pack2(bf2f((unsigned short)kv[6]) + f1.z, bf2f((unsigned short)kv[7]) + f1.w);
      *(uint4*)&sm.sK[p * 40 + seg * 8] = w;
    }
    for (int t = tid; t < 448; t += 256) {
      int c = div14(t), i = t - c * 14;
      int pix0 = (b * 128 + ybase + i) * 128 + xbase;
      const unsigned int* src = (const unsigned int*)(XVt + ((hc + c) << 16) + pix0 - 1);
      unsigned int d[8];
#pragma unroll
      for (int k = 0; k < 8; ++k) d[k] = src[k];
      int base = c * 232 + i * 14;
#pragma unroll
      for (int k = 0; k < 7; ++k)
        *(unsigned int*)&sm.sVt[base + k * 2] = (d[k] >> 16) | (d[k + 1] << 16);
    }
  } else {
    for (int t = tid; t < 784; t += 256) {
      int p = t >> 2, seg = t & 3;
      int i = div14(p), j = p - i * 14;
      int y = ybase + i, x = xbase + j;
      uint4 w = {0u, 0u, 0u, 0u};
      if ((unsigned)y < 128u && (unsigned)x < 128u) {
        int pix = (b * 128 + y) * 128 + x;
        bf16x8 kv = *(const bf16x8*)&XK[(pix << 8) + hc + seg * 8];
        const float4* pk4 = (const float4*)(PK + (p << 8) + hc + seg * 8);
        float4 f0 = pk4[0], f1 = pk4[1];
        w.x = pack2(bf2f((unsigned short)kv[0]) + f0.x, bf2f((unsigned short)kv[1]) + f0.y);
        w.y = pack2(bf2f((unsigned short)kv[2]) + f0.z, bf2f((unsigned short)kv[3]) + f0.w);
        w.z = pack2(bf2f((unsigned short)kv[4]) + f1.x, bf2f((unsigned short)kv[5]) + f1.y);
        w.w = pack2(bf2f((unsigned short)kv[6]) + f1.z, bf2f((unsigned short)kv[7]) + f1.w);
      }
      *(uint4*)&sm.sK[p * 40 + seg * 8] = w;
    }
    for (int t = tid; t < 448; t += 256) {
      int c = div14(t), i = t - c * 14;
      int y = ybase + i;
      unsigned int o[7] = {0u, 0u, 0u, 0u, 0u, 0u, 0u};
      if ((unsigned)y < 128u) {
        const unsigned short* row = XVt + ((hc + c) << 16) + (b * 128 + y) * 128;
#pragma unroll
        for (int k = 0; k < 7; ++k) {
          int x0 = xbase + 2 * k, x1 = x0 + 1;
          unsigned int lo = ((unsigned)x0 < 128u) ? row[x0] : 0u;
          unsigned int hi = ((unsigned)x1 < 128u) ? row[x1] : 0u;
          o[k] = lo | (hi << 16);
        }
      }
      int base = c * 232 + i * 14;
#pragma unroll
      for (int k = 0; k < 7; ++k) *(unsigned int*)&sm.sVt[base + k * 2] = o[k];
    }
  }
  {
    int m = tid >> 2, seg = tid & 3;
    int pix = (b * 128 + wy * 8 + (m >> 3)) * 128 + wx * 8 + (m & 7);
    *(uint4*)&sm.sU[m * 40 + seg * 8] = *(const uint4*)&XQ[(pix << 8) + hc + seg * 8];
  }
  __syncthreads();

  bf16x8 aq = *(const bf16x8*)&sm.sU[(wave * 16 + r) * 40 + q * 8];
  f32x4 s[14];
#pragma unroll
  for (int nt = 0; nt < 14; ++nt) {
    bf16x8 bk = *(const bf16x8*)&sm.sK[(nt * 16 + r) * 40 + q * 8];
    f32x4 z = {0.f, 0.f, 0.f, 0.f};
    s[nt] = __builtin_amdgcn_mfma_f32_16x16x32_bf16(aq, bk, z, 0, 0, 0);
  }
  if (interior) {
#pragma unroll
    for (int nt = 0; nt < 12; ++nt)
#pragma unroll
      for (int g = 0; g < 4; ++g) s[nt][g] *= SCALE;
#pragma unroll
    for (int g = 0; g < 4; ++g) {
      s[12][g] = (r < 4) ? s[12][g] * SCALE : -1e30f;
      s[13][g] = -1e30f;
    }
  } else {
#pragma unroll
    for (int nt = 0; nt < 14; ++nt) {
      int n = nt * 16 + r;
      int i = div14(n), j = n - i * 14;
      int y = ybase + i, x = xbase + j;
      bool valid = (n < 196) && ((unsigned)y < 128u) && ((unsigned)x < 128u);
#pragma unroll
      for (int g = 0; g < 4; ++g) s[nt][g] = valid ? s[nt][g] * SCALE : -1e30f;
    }
  }
  float mx[4] = {-1e30f, -1e30f, -1e30f, -1e30f};
#pragma unroll
  for (int nt = 0; nt < 14; ++nt)
#pragma unroll
    for (int g = 0; g < 4; ++g) mx[g] = fmaxf(mx[g], s[nt][g]);
#pragma unroll
  for (int d = 1; d < 16; d <<= 1)
#pragma unroll
    for (int g = 0; g < 4; ++g) mx[g] = fmaxf(mx[g], __shfl_xor(mx[g], d));
  float sum[4] = {0.f, 0.f, 0.f, 0.f};
#pragma unroll
  for (int nt = 0; nt < 14; ++nt)
#pragma unroll
    for (int g = 0; g < 4; ++g) {
      float e = __expf(s[nt][g] - mx[g]);
      s[nt][g] = e; sum[g] += e;
    }
#pragma unroll
  for (int d = 1; d < 16; d <<= 1)
#pragma unroll
    for (int g = 0; g < 4; ++g) sum[g] += __shfl_xor(sum[g], d);
  float inv[4];
#pragma unroll
  for (int g = 0; g < 4; ++g) inv[g] = 1.f / sum[g];
#pragma unroll
  for (int nt = 0; nt < 14; ++nt)
#pragma unroll
    for (int g = 0; g < 4; ++g) s[nt][g] *= inv[g];

  f32x4 ov[2];
  ov[0] = (f32x4){0.f, 0.f, 0.f, 0.f}; ov[1] = ov[0];
#pragma unroll
  for (int ck = 0; ck < 7; ++ck) {
#pragma unroll
    for (int tq = 0; tq < 2; ++tq)
#pragma unroll
      for (int g = 0; g < 4; ++g)
        sm.sU[(wave * 16 + q * 4 + g) * 40 + tq * 16 + r] = f2bf(s[ck * 2 + tq][g]);
    bf16x8 ap = *(const bf16x8*)&sm.sU[(wave * 16 + r) * 40 + q * 8];
#pragma unroll
    for (int t2 = 0; t2 < 2; ++t2) {
      bf16x8 bv = *(const bf16x8*)&sm.sVt[(t2 * 16 + r) * 232 + ck * 32 + q * 8];
      ov[t2] = __builtin_amdgcn_mfma_f32_16x16x32_bf16(ap, bv, ov[t2], 0, 0, 0);
    }
  }
#pragma unroll
  for (int t2 = 0; t2 < 2; ++t2)
#pragma unroll
    for (int g = 0; g < 4; ++g)
      sm.sU[(wave * 16 + q * 4 + g) * 40 + t2 * 16 + r] = f2bf(ov[t2][g]);
  {
    int m = tid >> 2, seg = tid & 3;
    int pix = (b * 128 + wy * 8 + (m >> 3)) * 128 + wx * 8 + (m & 7);
    bf16x8 o8 = *(const bf16x8*)&sm.sU[m * 40 + seg * 8];
    *(uint4*)&XO[(pix << 8) + hc + seg * 8] = *(uint4*)&o8;
  }
}

// ---------------- out_proj: 1D grid 1024; M=128, N=128; XCD-gather swizzle ----------------
__global__ __launch_bounds__(256, 3) void out_proj_kernel(
    const unsigned short* __restrict__ XO, const unsigned short* __restrict__ Wt,
    const float* __restrict__ bp, float* __restrict__ out) {
  __shared__ unsigned short sA[128 * 40];
  __shared__ unsigned short sB[128 * 40];
  const int bid = blockIdx.x;
  const int xcd = bid & 7, rowid = bid >> 3;  // rowid 0..127
  const int s2 = rowid & 1, gg = rowid >> 1;  // gg 0..63
  const int g = gg * 8 + xcd;                 // m-tile 0..511
  const int m0 = g << 7, n0 = s2 << 7;
  const int tid = threadIdx.x;
  const int wave = tid >> 6, lane = tid & 63, q = lane >> 4, r = lane & 15;

  const int rowA = tid >> 2, segA = tid & 3;
  const unsigned short* aptr = XO + ((m0 + rowA) << 8) + segA * 8;  // + kc*32
  const int rowB = tid >> 1, segB = (tid & 1) << 4;
  const unsigned short* bptr = Wt + 3 * 65536 + n0 * 32 + tid * 16;  // + kc*8192

  f32x4 acc[2][8];
#pragma unroll
  for (int nt = 0; nt < 8; ++nt) {
    float bv = bp[n0 + nt * 16 + r];
    acc[0][nt] = (f32x4){bv, bv, bv, bv};
    acc[1][nt] = (f32x4){bv, bv, bv, bv};
  }

  uint4 pa0 = *(const uint4*)(aptr);
  uint4 pa1 = *(const uint4*)(aptr + 16384);
  uint4 b0 = *(const uint4*)(bptr);
  uint4 b1 = *(const uint4*)(bptr + 8);

  for (int kc = 0; kc < 8; ++kc) {
    if (kc) __syncthreads();
    *(uint4*)&sA[rowA * 40 + segA * 8] = pa0;
    *(uint4*)&sA[(rowA + 64) * 40 + segA * 8] = pa1;
    *(uint4*)&sB[rowB * 40 + segB] = b0;
    *(uint4*)&sB[rowB * 40 + segB + 8] = b1;
    __syncthreads();
    if (kc < 7) {
      const unsigned short* ap = aptr + (kc + 1) * 32;
      pa0 = *(const uint4*)(ap);
      pa1 = *(const uint4*)(ap + 16384);
      const unsigned short* bpc = bptr + (kc + 1) * 8192;
      b0 = *(const uint4*)(bpc);
      b1 = *(const uint4*)(bpc + 8);
    }
    bf16x8 a0 = *(const bf16x8*)&sA[(wave * 32 + r) * 40 + q * 8];
    bf16x8 a1 = *(const bf16x8*)&sA[(wave * 32 + 16 + r) * 40 + q * 8];
#pragma unroll
    for (int nt = 0; nt < 8; ++nt) {
      bf16x8 bw = *(const bf16x8*)&sB[(nt * 16 + r) * 40 + q * 8];
      acc[0][nt] = __builtin_amdgcn_mfma_f32_16x16x32_bf16(a0, bw, acc[0][nt], 0, 0, 0);
      acc[1][nt] = __builtin_amdgcn_mfma_f32_16x16x32_bf16(a1, bw, acc[1][nt], 0, 0, 0);
    }
  }
#pragma unroll
  for (int mt = 0; mt < 2; ++mt)
#pragma unroll
    for (int nt = 0; nt < 8; ++nt)
#pragma unroll
      for (int g2 = 0; g2 < 4; ++g2) {
        int row = m0 + wave * 32 + mt * 16 + q * 4 + g2;
        out[(row << 8) + n0 + nt * 16 + r] = acc[mt][nt][g2];
      }
}

extern "C" void kernel_launch(void* const* d_in, const int* in_sizes, int n_in,
                              void* d_out, int out_size, void* d_ws, size_t ws_size,
                              hipStream_t stream) {
  (void)in_sizes; (void)n_in; (void)out_size;
  const float* xg = (const float*)d_in[0];
  const float* Wq = (const float*)d_in[1];
  const float* Wk = (const float*)d_in[2];
  const float* Wv = (const float*)d_in[3];
  const float* Wp = (const float*)d_in[4];
  const float* bp = (const float*)d_in[5];
  float* out = (float*)d_out;

  // ws layout (bytes), NEED = 101466112:
  //   XQO 0..33554432 | XK ..67108864 | XVt ..100663296 | Wt' ..101187584
  //   PK ..101400576 | PQ ..101466112
  if (ws_size < 101466112u) return;

  char* ws = (char*)d_ws;
  unsigned short* XQO = (unsigned short*)(ws);
  unsigned short* XK  = (unsigned short*)(ws + 33554432u);
  unsigned short* XVt = (unsigned short*)(ws + 67108864u);
  unsigned short* Wt  = (unsigned short*)(ws + 100663296u);
  float* PK = (float*)(ws + 101187584u);
  float* PQ = (float*)(ws + 101400576u);

  pos_proj_kernel<<<dim3(272), dim3(256), 0, stream>>>(Wq, Wk, PK, PQ);
  wtrans2_kernel<<<dim3(32), dim3(256), 0, stream>>>(Wq, Wk, Wv, Wp, Wt);
  qkv_gemm_kernel<<<dim3(3072), dim3(256), 0, stream>>>(xg, Wt, PQ, XQO, XK, XVt);
  halo_kernel<<<dim3(8192), dim3(256), 0, stream>>>(XQO, XK, XVt, PK, XQO);
  out_proj_kernel<<<dim3(1024), dim3(256), 0, stream>>>(XQO, Wt, bp, out);
}

// Round 12
// 308.343 us; speedup vs baseline: 1.1622x; 1.0439x over previous
//
#include <hip/hip_runtime.h>

// HaloAttn on MI355X (gfx950). f32 in/out, bf16 MFMA internals.
// R12: halo decode reverted to R8 (R11 head-gather swizzle cost ~12us total —
//   it broke adjacent-window wx-locality). NEW: halo K-staging uses
//   v_cvt_pk_bf16_f32 (1 op) instead of manual pack2 (~7 ops) — halo profiled
//   VALUBusy 53% (R11), staging repack is the biggest reducible VALU block.
//   qkv/out_proj bit-identical to R8 (104us, FETCH 35MB — don't perturb).

using bf16x8 = __attribute__((ext_vector_type(8))) short;
using f32x4  = __attribute__((ext_vector_type(4))) float;

__device__ __forceinline__ float bf2f(unsigned short u) {
  return __uint_as_float(((unsigned int)u) << 16);
}
__device__ __forceinline__ unsigned short f2bf(float f) {
  unsigned int x = __float_as_uint(f);
  x += 0x7fffu + ((x >> 16) & 1u);
  return (unsigned short)(x >> 16);
}
__device__ __forceinline__ unsigned int pack2(float a, float b) {
  return (unsigned int)f2bf(a) | ((unsigned int)f2bf(b) << 16);
}
// gfx950 packed f32->bf16 (RNE), lo=a hi=b. HW-verified (learn_hip m214v22).
__device__ __forceinline__ unsigned int cvtpk2(float a, float b) {
  unsigned int r;
  asm("v_cvt_pk_bf16_f32 %0, %1, %2" : "=v"(r) : "v"(a), "v"(b));
  return r;
}
__device__ __forceinline__ int div14(int p) { return (p * 4682) >> 16; }

// ---------------- pos_proj ----------------
__global__ __launch_bounds__(256) void pos_proj_kernel(
    const float* __restrict__ Wq, const float* __restrict__ Wk,
    float* __restrict__ PK, float* __restrict__ PQ) {
  __shared__ float pr[256];
  const int row = blockIdx.x, o = threadIdx.x;
  const float* Wm;
  float* dst;
  int ii, jj;
  if (row < 208) {
    if (row >= 196) { PK[row * 256 + o] = 0.f; return; }
    ii = row / 14; jj = row % 14;
    Wm = Wk; dst = PK + row * 256;
  } else {
    int qp = row - 208;
    ii = (qp >> 3) + 3; jj = (qp & 7) + 3;
    Wm = Wq; dst = PQ + qp * 256;
  }
  const int cl = o & 127, mfreq = cl >> 1;
  float t = powf(10000.f, (float)mfreq * (1.f / 64.f));
  float base = (o < 128) ? (float)(ii + 1) : (float)(jj + 1);
  float arg = base * (6.283185307179586f / 14.000001f) / t;
  pr[o] = (cl & 1) ? cosf(arg) : sinf(arg);
  __syncthreads();
  float acc = 0.f;
  for (int c = 0; c < 256; ++c) acc = fmaf(pr[c], Wm[c * 256 + o], acc);
  dst[o] = acc;
}

// ---------------- wtrans2: Wt'[mat][kc][n][32] = bf16(W[kc*32+kk][n]) ----------------
__global__ __launch_bounds__(256) void wtrans2_kernel(
    const float* __restrict__ Wq, const float* __restrict__ Wk,
    const float* __restrict__ Wv, const float* __restrict__ Wp,
    unsigned short* __restrict__ Wt) {
  __shared__ unsigned short sW[256 * 40];  // [n][kk], pad 40
  const int mat = blockIdx.x >> 3, kc = blockIdx.x & 7;
  const float* src = (mat == 0) ? Wq : (mat == 1) ? Wk : (mat == 2) ? Wv : Wp;
  const int tid = threadIdx.x;
  for (int t = tid; t < 2048; t += 256) {
    int k = t >> 6, sg = t & 63;
    float4 v = *(const float4*)&src[(kc * 32 + k) * 256 + sg * 4];
    sW[(sg * 4 + 0) * 40 + k] = f2bf(v.x);
    sW[(sg * 4 + 1) * 40 + k] = f2bf(v.y);
    sW[(sg * 4 + 2) * 40 + k] = f2bf(v.z);
    sW[(sg * 4 + 3) * 40 + k] = f2bf(v.w);
  }
  __syncthreads();
  unsigned short* dst = Wt + mat * 65536 + kc * 8192;
  for (int t = tid; t < 1024; t += 256) {
    int n = t >> 2, sg = t & 3;
    *(uint4*)&dst[n * 32 + sg * 8] = *(const uint4*)&sW[n * 40 + sg * 8];
  }
}

// ---------------- qkv_gemm: 1D grid 3072; M=128, N=128, K in 8 chunks of 32 ----------------
// XCD-gather decode: the 6 blocks (s=mat*2+n0half) of m-tile g sit at ids
// {(6*(g/8)+s)*8 + g%8} -> same XCD, <=48 ids apart.
struct QkvLds {
  union {
    struct {
      unsigned short sA[128 * 40];  // A-tile bf16 [row][k32], stride 40
      unsigned short sB[128 * 40];  // B-tile bf16 [n][k32], stride 40
    } s;
    unsigned short sT[64 * 136];    // V-transpose chunk [ch64][pix128], stride 136
  } u;
  float sPQ[8 * 128];               // PQ slice cols n0..n0+127 (mat 0 only)
};

__global__ __launch_bounds__(256, 3) void qkv_gemm_kernel(
    const float* __restrict__ xg, const unsigned short* __restrict__ Wt,
    const float* __restrict__ PQ,
    unsigned short* __restrict__ XQ, unsigned short* __restrict__ XK,
    unsigned short* __restrict__ XVt) {
  __shared__ QkvLds sm;
  const int bid = blockIdx.x;
  const int xcd = bid & 7, rowid = bid >> 3;   // rowid 0..383
  const int s6 = rowid % 6, gg = rowid / 6;    // s6: mat*2+n0half, gg 0..63
  const int g = gg * 8 + xcd;                  // m-tile 0..511
  const int mat = s6 >> 1;
  const int m0 = g << 7;
  const int n0 = (s6 & 1) << 7;
  const int tid = threadIdx.x;
  const int wave = tid >> 6, lane = tid & 63, q = lane >> 4, r = lane & 15;

  if (mat == 0) {  // stage PQ rows (y&7)*8..+8, cols n0..n0+127
    const int y7 = (m0 >> 7) & 7;
    const int rr = tid >> 5, cc = tid & 31;
    *(float4*)&sm.sPQ[rr * 128 + cc * 4] =
        *(const float4*)&PQ[(y7 * 8 + rr) * 256 + n0 + cc * 4];
  }

  const int rowA = tid >> 2, segA = tid & 3;
  const float* aptr = xg + ((m0 + rowA) << 8) + segA * 8;  // + kc*32
  const int rowB = tid >> 1, segB = (tid & 1) << 4;
  const unsigned short* bptr = Wt + mat * 65536 + n0 * 32 + tid * 16;  // + kc*8192

  f32x4 acc[2][8];
#pragma unroll
  for (int mt = 0; mt < 2; ++mt)
#pragma unroll
    for (int nt = 0; nt < 8; ++nt) acc[mt][nt] = (f32x4){0.f, 0.f, 0.f, 0.f};

  // prefetch chunk 0
  float4 a00 = *(const float4*)(aptr);
  float4 a01 = *(const float4*)(aptr + 4);
  float4 a10 = *(const float4*)(aptr + 16384);
  float4 a11 = *(const float4*)(aptr + 16384 + 4);
  uint4 b0 = *(const uint4*)(bptr);
  uint4 b1 = *(const uint4*)(bptr + 8);

  for (int kc = 0; kc < 8; ++kc) {
    if (kc) __syncthreads();  // frag reads of kc-1 complete
    {
      uint4 w;
      w.x = pack2(a00.x, a00.y); w.y = pack2(a00.z, a00.w);
      w.z = pack2(a01.x, a01.y); w.w = pack2(a01.z, a01.w);
      *(uint4*)&sm.u.s.sA[rowA * 40 + segA * 8] = w;
      w.x = pack2(a10.x, a10.y); w.y = pack2(a10.z, a10.w);
      w.z = pack2(a11.x, a11.y); w.w = pack2(a11.z, a11.w);
      *(uint4*)&sm.u.s.sA[(rowA + 64) * 40 + segA * 8] = w;
      *(uint4*)&sm.u.s.sB[rowB * 40 + segB] = b0;
      *(uint4*)&sm.u.s.sB[rowB * 40 + segB + 8] = b1;
    }
    __syncthreads();
    if (kc < 7) {  // issue next-chunk loads; in flight during MFMAs + barrier
      const float* ap = aptr + (kc + 1) * 32;
      a00 = *(const float4*)(ap);
      a01 = *(const float4*)(ap + 4);
      a10 = *(const float4*)(ap + 16384);
      a11 = *(const float4*)(ap + 16384 + 4);
      const unsigned short* bp = bptr + (kc + 1) * 8192;
      b0 = *(const uint4*)(bp);
      b1 = *(const uint4*)(bp + 8);
    }
    bf16x8 a0 = *(const bf16x8*)&sm.u.s.sA[(wave * 32 + r) * 40 + q * 8];
    bf16x8 a1 = *(const bf16x8*)&sm.u.s.sA[(wave * 32 + 16 + r) * 40 + q * 8];
#pragma unroll
    for (int nt = 0; nt < 8; ++nt) {
      bf16x8 bw = *(const bf16x8*)&sm.u.s.sB[(nt * 16 + r) * 40 + q * 8];
      acc[0][nt] = __builtin_amdgcn_mfma_f32_16x16x32_bf16(a0, bw, acc[0][nt], 0, 0, 0);
      acc[1][nt] = __builtin_amdgcn_mfma_f32_16x16x32_bf16(a1, bw, acc[1][nt], 0, 0, 0);
    }
  }

  if (mat == 2) {
    // V transposed store via LDS: 2 chunks of 64 channels (n0 half), coalesced rows
    __syncthreads();  // all LDS frag reads done before sT overwrite
#pragma unroll
    for (int c4 = 0; c4 < 2; ++c4) {
      if (c4) __syncthreads();
#pragma unroll
      for (int mt = 0; mt < 2; ++mt)
#pragma unroll
        for (int n4 = 0; n4 < 4; ++n4)
#pragma unroll
          for (int g2 = 0; g2 < 4; ++g2) {
            int ch = n4 * 16 + r;
            int pr = wave * 32 + mt * 16 + q * 4 + g2;
            sm.u.sT[ch * 136 + pr] = f2bf(acc[mt][c4 * 4 + n4][g2]);
          }
      __syncthreads();
      for (int t = tid; t < 1024; t += 256) {
        int ch = t >> 4, sg = t & 15;
        *(uint4*)&XVt[((n0 + c4 * 64 + ch) << 16) + m0 + sg * 8] =
            *(const uint4*)&sm.u.sT[ch * 136 + sg * 8];
      }
    }
  } else {
    unsigned short* dst = (mat == 0) ? XQ : XK;
#pragma unroll
    for (int mt = 0; mt < 2; ++mt)
#pragma unroll
      for (int nt = 0; nt < 8; ++nt)
#pragma unroll
        for (int g2 = 0; g2 < 4; ++g2) {
          int lrow = wave * 32 + mt * 16 + q * 4 + g2;
          float v = acc[mt][nt][g2];
          if (mat == 0) v += sm.sPQ[(lrow & 7) * 128 + nt * 16 + r];
          dst[((m0 + lrow) << 8) + n0 + nt * 16 + r] = f2bf(v);
        }
  }
}

// ---------------- halo: one WG per (window, head); grid 8192 (R8 decode) ----------------
struct alignas(16) SMH {
  unsigned short sK[196 * 40];
  unsigned short sVt[32 * 232];
  unsigned short sU[64 * 40];
};

__global__ __launch_bounds__(256, 4) void halo_kernel(
    const unsigned short* XQ,           // aliases XO
    const unsigned short* __restrict__ XK,
    const unsigned short* __restrict__ XVt,
    const float* __restrict__ PK,
    unsigned short* XO) {
  __shared__ SMH sm;
  const int wid = blockIdx.x;
  const int h = wid & 7, win = wid >> 3;
  const int b = win >> 8, widx = win & 255;
  const int wy = widx >> 4, wx = widx & 15;
  const int hc = h * 32;
  const int tid = threadIdx.x;
  const int wave = tid >> 6, lane = tid & 63, q = lane >> 4, r = lane & 15;
  const bool interior = (unsigned)(wy - 1) < 14u && (unsigned)(wx - 1) < 14u;
  const int ybase = wy * 8 - 3, xbase = wx * 8 - 3;
  constexpr float SCALE = 0.17677669529663687f;

  for (int idx = tid; idx < 1152; idx += 256) {
    int rr = idx / 36, c2 = idx - rr * 36;
    sm.sVt[rr * 232 + 196 + c2] = 0;
  }

  if (interior) {
    for (int t = tid; t < 784; t += 256) {
      int p = t >> 2, seg = t & 3;
      int i = div14(p), j = p - i * 14;
      int pix = (b * 128 + ybase + i) * 128 + xbase + j;
      bf16x8 kv = *(const bf16x8*)&XK[(pix << 8) + hc + seg * 8];
      const float4* pk4 = (const float4*)(PK + (p << 8) + hc + seg * 8);
      float4 f0 = pk4[0], f1 = pk4[1];
      uint4 w;
      w.x = cvtpk2(bf2f((unsigned short)kv[0]) + f0.x, bf2f((unsigned short)kv[1]) + f0.y);
      w.y = cvtpk2(bf2f((unsigned short)kv[2]) + f0.z, bf2f((unsigned short)kv[3]) + f0.w);
      w.z = cvtpk2(bf2f((unsigned short)kv[4]) + f1.x, bf2f((unsigned short)kv[5]) + f1.y);
      w.w = cvtpk2(bf2f((unsigned short)kv[6]) + f1.z, bf2f((unsigned short)kv[7]) + f1.w);
      *(uint4*)&sm.sK[p * 40 + seg * 8] = w;
    }
    for (int t = tid; t < 448; t += 256) {
      int c = div14(t), i = t - c * 14;
      int pix0 = (b * 128 + ybase + i) * 128 + xbase;
      const unsigned int* src = (const unsigned int*)(XVt + ((hc + c) << 16) + pix0 - 1);
      unsigned int d[8];
#pragma unroll
      for (int k = 0; k < 8; ++k) d[k] = src[k];
      int base = c * 232 + i * 14;
#pragma unroll
      for (int k = 0; k < 7; ++k)
        *(unsigned int*)&sm.sVt[base + k * 2] = (d[k] >> 16) | (d[k + 1] << 16);
    }
  } else {
    for (int t = tid; t < 784; t += 256) {
      int p = t >> 2, seg = t & 3;
      int i = div14(p), j = p - i * 14;
      int y = ybase + i, x = xbase + j;
      uint4 w = {0u, 0u, 0u, 0u};
      if ((unsigned)y < 128u && (unsigned)x < 128u) {
        int pix = (b * 128 + y) * 128 + x;
        bf16x8 kv = *(const bf16x8*)&XK[(pix << 8) + hc + seg * 8];
        const float4* pk4 = (const float4*)(PK + (p << 8) + hc + seg * 8);
        float4 f0 = pk4[0], f1 = pk4[1];
        w.x = cvtpk2(bf2f((unsigned short)kv[0]) + f0.x, bf2f((unsigned short)kv[1]) + f0.y);
        w.y = cvtpk2(bf2f((unsigned short)kv[2]) + f0.z, bf2f((unsigned short)kv[3]) + f0.w);
        w.z = cvtpk2(bf2f((unsigned short)kv[4]) + f1.x, bf2f((unsigned short)kv[5]) + f1.y);
        w.w = cvtpk2(bf2f((unsigned short)kv[6]) + f1.z, bf2f((unsigned short)kv[7]) + f1.w);
      }
      *(uint4*)&sm.sK[p * 40 + seg * 8] = w;
    }
    for (int t = tid; t < 448; t += 256) {
      int c = div14(t), i = t - c * 14;
      int y = ybase + i;
      unsigned int o[7] = {0u, 0u, 0u, 0u, 0u, 0u, 0u};
      if ((unsigned)y < 128u) {
        const unsigned short* row = XVt + ((hc + c) << 16) + (b * 128 + y) * 128;
#pragma unroll
        for (int k = 0; k < 7; ++k) {
          int x0 = xbase + 2 * k, x1 = x0 + 1;
          unsigned int lo = ((unsigned)x0 < 128u) ? row[x0] : 0u;
          unsigned int hi = ((unsigned)x1 < 128u) ? row[x1] : 0u;
          o[k] = lo | (hi << 16);
        }
      }
      int base = c * 232 + i * 14;
#pragma unroll
      for (int k = 0; k < 7; ++k) *(unsigned int*)&sm.sVt[base + k * 2] = o[k];
    }
  }
  {
    int m = tid >> 2, seg = tid & 3;
    int pix = (b * 128 + wy * 8 + (m >> 3)) * 128 + wx * 8 + (m & 7);
    *(uint4*)&sm.sU[m * 40 + seg * 8] = *(const uint4*)&XQ[(pix << 8) + hc + seg * 8];
  }
  __syncthreads();

  bf16x8 aq = *(const bf16x8*)&sm.sU[(wave * 16 + r) * 40 + q * 8];
  f32x4 s[14];
#pragma unroll
  for (int nt = 0; nt < 14; ++nt) {
    bf16x8 bk = *(const bf16x8*)&sm.sK[(nt * 16 + r) * 40 + q * 8];
    f32x4 z = {0.f, 0.f, 0.f, 0.f};
    s[nt] = __builtin_amdgcn_mfma_f32_16x16x32_bf16(aq, bk, z, 0, 0, 0);
  }
  if (interior) {
#pragma unroll
    for (int nt = 0; nt < 12; ++nt)
#pragma unroll
      for (int g = 0; g < 4; ++g) s[nt][g] *= SCALE;
#pragma unroll
    for (int g = 0; g < 4; ++g) {
      s[12][g] = (r < 4) ? s[12][g] * SCALE : -1e30f;
      s[13][g] = -1e30f;
    }
  } else {
#pragma unroll
    for (int nt = 0; nt < 14; ++nt) {
      int n = nt * 16 + r;
      int i = div14(n), j = n - i * 14;
      int y = ybase + i, x = xbase + j;
      bool valid = (n < 196) && ((unsigned)y < 128u) && ((unsigned)x < 128u);
#pragma unroll
      for (int g = 0; g < 4; ++g) s[nt][g] = valid ? s[nt][g] * SCALE : -1e30f;
    }
  }
  float mx[4] = {-1e30f, -1e30f, -1e30f, -1e30f};
#pragma unroll
  for (int nt = 0; nt < 14; ++nt)
#pragma unroll
    for (int g = 0; g < 4; ++g) mx[g] = fmaxf(mx[g], s[nt][g]);
#pragma unroll
  for (int d = 1; d < 16; d <<= 1)
#pragma unroll
    for (int g = 0; g < 4; ++g) mx[g] = fmaxf(mx[g], __shfl_xor(mx[g], d));
  float sum[4] = {0.f, 0.f, 0.f, 0.f};
#pragma unroll
  for (int nt = 0; nt < 14; ++nt)
#pragma unroll
    for (int g = 0; g < 4; ++g) {
      float e = __expf(s[nt][g] - mx[g]);
      s[nt][g] = e; sum[g] += e;
    }
#pragma unroll
  for (int d = 1; d < 16; d <<= 1)
#pragma unroll
    for (int g = 0; g < 4; ++g) sum[g] += __shfl_xor(sum[g], d);
  float inv[4];
#pragma unroll
  for (int g = 0; g < 4; ++g) inv[g] = 1.f / sum[g];
#pragma unroll
  for (int nt = 0; nt < 14; ++nt)
#pragma unroll
    for (int g = 0; g < 4; ++g) s[nt][g] *= inv[g];

  f32x4 ov[2];
  ov[0] = (f32x4){0.f, 0.f, 0.f, 0.f}; ov[1] = ov[0];
#pragma unroll
  for (int ck = 0; ck < 7; ++ck) {
#pragma unroll
    for (int tq = 0; tq < 2; ++tq)
#pragma unroll
      for (int g = 0; g < 4; ++g)
        sm.sU[(wave * 16 + q * 4 + g) * 40 + tq * 16 + r] = f2bf(s[ck * 2 + tq][g]);
    bf16x8 ap = *(const bf16x8*)&sm.sU[(wave * 16 + r) * 40 + q * 8];
#pragma unroll
    for (int t2 = 0; t2 < 2; ++t2) {
      bf16x8 bv = *(const bf16x8*)&sm.sVt[(t2 * 16 + r) * 232 + ck * 32 + q * 8];
      ov[t2] = __builtin_amdgcn_mfma_f32_16x16x32_bf16(ap, bv, ov[t2], 0, 0, 0);
    }
  }
#pragma unroll
  for (int t2 = 0; t2 < 2; ++t2)
#pragma unroll
    for (int g = 0; g < 4; ++g)
      sm.sU[(wave * 16 + q * 4 + g) * 40 + t2 * 16 + r] = f2bf(ov[t2][g]);
  {
    int m = tid >> 2, seg = tid & 3;
    int pix = (b * 128 + wy * 8 + (m >> 3)) * 128 + wx * 8 + (m & 7);
    bf16x8 o8 = *(const bf16x8*)&sm.sU[m * 40 + seg * 8];
    *(uint4*)&XO[(pix << 8) + hc + seg * 8] = *(uint4*)&o8;
  }
}

// ---------------- out_proj: 1D grid 1024; M=128, N=128; XCD-gather swizzle ----------------
__global__ __launch_bounds__(256, 3) void out_proj_kernel(
    const unsigned short* __restrict__ XO, const unsigned short* __restrict__ Wt,
    const float* __restrict__ bp, float* __restrict__ out) {
  __shared__ unsigned short sA[128 * 40];
  __shared__ unsigned short sB[128 * 40];
  const int bid = blockIdx.x;
  const int xcd = bid & 7, rowid = bid >> 3;  // rowid 0..127
  const int s2 = rowid & 1, gg = rowid >> 1;  // gg 0..63
  const int g = gg * 8 + xcd;                 // m-tile 0..511
  const int m0 = g << 7, n0 = s2 << 7;
  const int tid = threadIdx.x;
  const int wave = tid >> 6, lane = tid & 63, q = lane >> 4, r = lane & 15;

  const int rowA = tid >> 2, segA = tid & 3;
  const unsigned short* aptr = XO + ((m0 + rowA) << 8) + segA * 8;  // + kc*32
  const int rowB = tid >> 1, segB = (tid & 1) << 4;
  const unsigned short* bptr = Wt + 3 * 65536 + n0 * 32 + tid * 16;  // + kc*8192

  f32x4 acc[2][8];
#pragma unroll
  for (int nt = 0; nt < 8; ++nt) {
    float bv = bp[n0 + nt * 16 + r];
    acc[0][nt] = (f32x4){bv, bv, bv, bv};
    acc[1][nt] = (f32x4){bv, bv, bv, bv};
  }

  uint4 pa0 = *(const uint4*)(aptr);
  uint4 pa1 = *(const uint4*)(aptr + 16384);
  uint4 b0 = *(const uint4*)(bptr);
  uint4 b1 = *(const uint4*)(bptr + 8);

  for (int kc = 0; kc < 8; ++kc) {
    if (kc) __syncthreads();
    *(uint4*)&sA[rowA * 40 + segA * 8] = pa0;
    *(uint4*)&sA[(rowA + 64) * 40 + segA * 8] = pa1;
    *(uint4*)&sB[rowB * 40 + segB] = b0;
    *(uint4*)&sB[rowB * 40 + segB + 8] = b1;
    __syncthreads();
    if (kc < 7) {
      const unsigned short* ap = aptr + (kc + 1) * 32;
      pa0 = *(const uint4*)(ap);
      pa1 = *(const uint4*)(ap + 16384);
      const unsigned short* bpc = bptr + (kc + 1) * 8192;
      b0 = *(const uint4*)(bpc);
      b1 = *(const uint4*)(bpc + 8);
    }
    bf16x8 a0 = *(const bf16x8*)&sA[(wave * 32 + r) * 40 + q * 8];
    bf16x8 a1 = *(const bf16x8*)&sA[(wave * 32 + 16 + r) * 40 + q * 8];
#pragma unroll
    for (int nt = 0; nt < 8; ++nt) {
      bf16x8 bw = *(const bf16x8*)&sB[(nt * 16 + r) * 40 + q * 8];
      acc[0][nt] = __builtin_amdgcn_mfma_f32_16x16x32_bf16(a0, bw, acc[0][nt], 0, 0, 0);
      acc[1][nt] = __builtin_amdgcn_mfma_f32_16x16x32_bf16(a1, bw, acc[1][nt], 0, 0, 0);
    }
  }
#pragma unroll
  for (int mt = 0; mt < 2; ++mt)
#pragma unroll
    for (int nt = 0; nt < 8; ++nt)
#pragma unroll
      for (int g2 = 0; g2 < 4; ++g2) {
        int row = m0 + wave * 32 + mt * 16 + q * 4 + g2;
        out[(row << 8) + n0 + nt * 16 + r] = acc[mt][nt][g2];
      }
}

extern "C" void kernel_launch(void* const* d_in, const int* in_sizes, int n_in,
                              void* d_out, int out_size, void* d_ws, size_t ws_size,
                              hipStream_t stream) {
  (void)in_sizes; (void)n_in; (void)out_size;
  const float* xg = (const float*)d_in[0];
  const float* Wq = (const float*)d_in[1];
  const float* Wk = (const float*)d_in[2];
  const float* Wv = (const float*)d_in[3];
  const float* Wp = (const float*)d_in[4];
  const float* bp = (const float*)d_in[5];
  float* out = (float*)d_out;

  // ws layout (bytes), NEED = 101466112:
  //   XQO 0..33554432 | XK ..67108864 | XVt ..100663296 | Wt' ..101187584
  //   PK ..101400576 | PQ ..101466112
  if (ws_size < 101466112u) return;

  char* ws = (char*)d_ws;
  unsigned short* XQO = (unsigned short*)(ws);
  unsigned short* XK  = (unsigned short*)(ws + 33554432u);
  unsigned short* XVt = (unsigned short*)(ws + 67108864u);
  unsigned short* Wt  = (unsigned short*)(ws + 100663296u);
  float* PK = (float*)(ws + 101187584u);
  float* PQ = (float*)(ws + 101400576u);

  pos_proj_kernel<<<dim3(272), dim3(256), 0, stream>>>(Wq, Wk, PK, PQ);
  wtrans2_kernel<<<dim3(32), dim3(256), 0, stream>>>(Wq, Wk, Wv, Wp, Wt);
  qkv_gemm_kernel<<<dim3(3072), dim3(256), 0, stream>>>(xg, Wt, PQ, XQO, XK, XVt);
  halo_kernel<<<dim3(8192), dim3(256), 0, stream>>>(XQO, XK, XVt, PK, XQO);
  out_proj_kernel<<<dim3(1024), dim3(256), 0, stream>>>(XQO, Wt, bp, out);
}